// Round 4
// baseline (3643.761 us; speedup 1.0000x reference)
//
#include <hip/hip_runtime.h>
#include <cmath>

#define KNN 20
#define NPTS 4096
#define BATCH 2
#define SLOPE 0.2f
#define BNEPS 1e-5
#define GTK 16

static __device__ __host__ inline int imin(int a, int b) { return a < b ? a : b; }

// ---------------- utility kernels ----------------
// x (B,3,N) -> xb (B,N,3)
__global__ void xtrans_kernel(const float* __restrict__ x, float* __restrict__ xb) {
  int i = blockIdx.x * 256 + threadIdx.x;
  if (i < BATCH * 3 * NPTS) {
    int b = i / (3 * NPTS);
    int r = i - b * 3 * NPTS;
    int c = r / NPTS;
    int n = r - c * NPTS;
    xb[((size_t)b * NPTS + n) * 3 + c] = x[i];
  }
}

// w (O,I) -> wt (I,O)
__global__ void wtrans_kernel(const float* __restrict__ w, float* __restrict__ wt, int O, int I) {
  int i = blockIdx.x * 256 + threadIdx.x;
  if (i < O * I) {
    int o = i / I, j = i - o * I;
    wt[(size_t)j * O + o] = w[i];
  }
}

// W (O, 2C) -> U (C, 2O): U[j][o]=W[o][j]; U[j][O+o]=W[o][C+j]-W[o][j]
__global__ void uprep_kernel(const float* __restrict__ W, float* __restrict__ U, int O, int C) {
  int i = blockIdx.x * 256 + threadIdx.x;
  if (i < C * O) {
    int j = i / O, o = i - j * O;
    float w1 = W[(size_t)o * 2 * C + j];
    float w2 = W[(size_t)o * 2 * C + C + j];
    U[(size_t)j * 2 * O + o] = w1;
    U[(size_t)j * 2 * O + O + o] = w2 - w1;
  }
}

// squared norms per point (fp64)
__global__ void xx_kernel(const float* __restrict__ X, int stride, int C, double* __restrict__ xx) {
  int i = blockIdx.x * 256 + threadIdx.x;
  if (i < BATCH * NPTS) {
    const float* r = X + (size_t)i * stride;
    double s = 0.0;
    for (int c = 0; c < C; ++c) s += (double)r[c] * (double)r[c];
    xx[i] = s;
  }
}

// ---------------- fp64-accurate distance GEMM ----------------
// dist[n][m] = (float)(2*sum_c A[n][c]*B[m][c] - xxA[n] - xxB[m]), fp64 accumulate.
// 64x64 tile, 4x4 micro, 256 threads.
__global__ __launch_bounds__(256) void dist64_kernel(const float* __restrict__ A, int lda,
                                                     const float* __restrict__ B, int ldb,
                                                     const double* __restrict__ xxA,
                                                     const double* __restrict__ xxB,
                                                     float* __restrict__ dist, int ldc, int K) {
  __shared__ double sA[GTK][66];
  __shared__ double sB[GTK][66];
  int t = threadIdx.x;
  int tx = t & 15, ty = t >> 4;
  int row0 = blockIdx.y * 64, col0 = blockIdx.x * 64;
  double acc[4][4] = {};

  for (int k0 = 0; k0 < K; k0 += GTK) {
    for (int e = t; e < 64 * GTK; e += 256) {
      int r = e >> 4, c = e & 15;
      bool ok = (k0 + c < K);
      sA[c][r] = ok ? (double)A[(size_t)(row0 + r) * lda + k0 + c] : 0.0;
      sB[c][r] = ok ? (double)B[(size_t)(col0 + r) * ldb + k0 + c] : 0.0;
    }
    __syncthreads();
#pragma unroll
    for (int kk = 0; kk < GTK; ++kk) {
      double a[4], b[4];
#pragma unroll
      for (int i = 0; i < 4; ++i) a[i] = sA[kk][ty * 4 + i];
#pragma unroll
      for (int j = 0; j < 4; ++j) b[j] = sB[kk][tx * 4 + j];
#pragma unroll
      for (int i = 0; i < 4; ++i)
#pragma unroll
        for (int j = 0; j < 4; ++j) acc[i][j] = fma(a[i], b[j], acc[i][j]);
    }
    __syncthreads();
  }

#pragma unroll
  for (int i = 0; i < 4; ++i) {
    int gr = row0 + ty * 4 + i;
    double xa = xxA[gr];
#pragma unroll
    for (int j = 0; j < 4; ++j) {
      int gc = col0 + tx * 4 + j;
      dist[(size_t)gr * ldc + gc] = (float)(2.0 * acc[i][j] - xa - xxB[gc]);
    }
  }
}

// ---------------- generic 128x128 fp32 GEMM, 8x8 micro (PQ + FC) ----------------
// C[M x N] = A[M x K] * B[K x N]; k-major swizzled LDS.
__global__ __launch_bounds__(256) void gemm128(const float* __restrict__ A, int lda,
                                               const float* __restrict__ B, int ldb,
                                               float* __restrict__ C, int ldc, int K) {
  __shared__ __align__(16) float sA[GTK][144];
  __shared__ __align__(16) float sB[GTK][144];
  int t = threadIdx.x;
  int tx = t & 15, ty = t >> 4;
  int row0 = blockIdx.y * 128, col0 = blockIdx.x * 128;
  float acc[8][8] = {};

  for (int k0 = 0; k0 < K; k0 += GTK) {
    bool fast = (k0 + GTK <= K);
    // stage A (transpose to k-major)
    if (fast) {
#pragma unroll
      for (int it = 0; it < 2; ++it) {
        int i = t + it * 256;
        int r = i >> 2, q = i & 3;
        const float4 av = *(const float4*)&A[(size_t)(row0 + r) * lda + k0 + q * 4];
        int pr = r + ((r >> 5) << 2);
        sA[q * 4 + 0][pr] = av.x;
        sA[q * 4 + 1][pr] = av.y;
        sA[q * 4 + 2][pr] = av.z;
        sA[q * 4 + 3][pr] = av.w;
      }
    } else {
#pragma unroll
      for (int it = 0; it < 2; ++it) {
        int i = t + it * 256;
        int r = i >> 2, q = i & 3;
        int pr = r + ((r >> 5) << 2);
#pragma unroll
        for (int j = 0; j < 4; ++j) {
          int k = q * 4 + j;
          sA[k][pr] = (k0 + k < K) ? A[(size_t)(row0 + r) * lda + k0 + k] : 0.f;
        }
      }
    }
    // stage B (already k-major in memory)
#pragma unroll
    for (int it = 0; it < 2; ++it) {
      int i = t + it * 256;
      int k = i >> 5, nq = (i & 31) * 4;
      int pc = nq + ((nq >> 5) << 2);
      float4 bv = make_float4(0.f, 0.f, 0.f, 0.f);
      if (k0 + k < K) bv = *(const float4*)&B[(size_t)(k0 + k) * ldb + col0 + nq];
      *(float4*)&sB[k][pc] = bv;
    }
    __syncthreads();
    int prA = ty * 8 + ((ty >> 2) << 2);
    int prB = tx * 8 + ((tx >> 2) << 2);
#pragma unroll
    for (int kk = 0; kk < GTK; ++kk) {
      float a[8], b[8];
      *(float4*)&a[0] = *(const float4*)&sA[kk][prA];
      *(float4*)&a[4] = *(const float4*)&sA[kk][prA + 4];
      *(float4*)&b[0] = *(const float4*)&sB[kk][prB];
      *(float4*)&b[4] = *(const float4*)&sB[kk][prB + 4];
#pragma unroll
      for (int i = 0; i < 8; ++i)
#pragma unroll
        for (int j = 0; j < 8; ++j) acc[i][j] += a[i] * b[j];
    }
    __syncthreads();
  }

#pragma unroll
  for (int i = 0; i < 8; ++i) {
    int gr = row0 + ty * 8 + i;
#pragma unroll
    for (int jq = 0; jq < 2; ++jq) {
      float4 o;
#pragma unroll
      for (int j = 0; j < 4; ++j) ((float*)&o)[j] = acc[i][jq * 4 + j];
      *(float4*)&C[(size_t)gr * ldc + col0 + tx * 8 + jq * 4] = o;
    }
  }
}

// ---------------- top-k: one wave per row, values in registers ----------------
__global__ __launch_bounds__(256) void topk_kernel(const float* __restrict__ dist,
                                                   int* __restrict__ idxout, int n0, int rows) {
  int wave = threadIdx.x >> 6, lane = threadIdx.x & 63;
  int row = blockIdx.x * 4 + wave;
  if (row >= rows) return;
  const float* d = dist + (size_t)row * NPTS;
  float v[16][4];
#pragma unroll
  for (int s = 0; s < 16; ++s) *(float4*)v[s] = *(const float4*)&d[s * 256 + lane * 4];
  int base = lane * 4;
  for (int it = 0; it < KNN; ++it) {
    float bv = v[0][0];
    int bi = base;
#pragma unroll
    for (int s = 0; s < 16; ++s)
#pragma unroll
      for (int c = 0; c < 4; ++c) {
        if (s == 0 && c == 0) continue;
        float x = v[s][c];
        if (x > bv) { bv = x; bi = s * 256 + base + c; }
      }
#pragma unroll
    for (int off = 1; off < 64; off <<= 1) {
      float ov = __shfl_xor(bv, off);
      int oi = __shfl_xor(bi, off);
      if (ov > bv || (ov == bv && oi < bi)) { bv = ov; bi = oi; }
    }
    if (lane == 0) idxout[(size_t)(n0 + row) * KNN + it] = bi;
#pragma unroll
    for (int s = 0; s < 16; ++s)
#pragma unroll
      for (int c = 0; c < 4; ++c)
        if (s * 256 + base + c == bi) v[s][c] = -__builtin_inff();
  }
}

// ---------------- gather-max + per-block fp64 BN partial stats ----------------
// h[n,k,o] = P[idx[n,k],o] + Q[n,o]; PQ row = [P | Q] (stride 2O). One wave per point.
// Block partials (fp64) to pbuf[blk][2*O] = [sum | sumsq].
template <int NO>
__global__ __launch_bounds__(256) void gathermax_kernel(const float* __restrict__ PQ,
                                                        const int* __restrict__ idx,
                                                        float* __restrict__ hmax, int O,
                                                        double* __restrict__ pbuf) {
  __shared__ double sh1[4][256];
  __shared__ double sh2[4][256];
  int t = threadIdx.x;
  int wave = t >> 6, lane = t & 63;
  int pt = blockIdx.x * 4 + wave;
  int b = pt >> 12;
  int O2 = 2 * O;
  int iv = idx[(size_t)pt * KNN + (lane % KNN)];
  const float* Qp = PQ + (size_t)pt * O2 + O + lane * NO;
  float q[NO], mx[NO];
  double s1[NO], s2[NO];
#pragma unroll
  for (int c = 0; c < NO; ++c) {
    q[c] = Qp[c];
    mx[c] = -__builtin_inff();
    s1[c] = 0.0;
    s2[c] = 0.0;
  }
#pragma unroll
  for (int k = 0; k < KNN; ++k) {
    int m = __shfl(iv, k);
    const float* Pp = PQ + ((size_t)(b << 12) + m) * O2 + lane * NO;
    float p[NO];
#pragma unroll
    for (int c = 0; c < NO; ++c) p[c] = Pp[c];
#pragma unroll
    for (int c = 0; c < NO; ++c) {
      float h = p[c] + q[c];
      mx[c] = fmaxf(mx[c], h);
      double hd = (double)h;
      s1[c] += hd;
      s2[c] += hd * hd;
    }
  }
  float* Hp = hmax + (size_t)pt * O + lane * NO;
#pragma unroll
  for (int c = 0; c < NO; ++c) {
    Hp[c] = mx[c];
    sh1[wave][lane * NO + c] = s1[c];
    sh2[wave][lane * NO + c] = s2[c];
  }
  __syncthreads();
  if (t < O) {
    double a = 0.0, bb = 0.0;
#pragma unroll
    for (int w = 0; w < 4; ++w) {
      a += sh1[w][t];
      bb += sh2[w][t];
    }
    pbuf[(size_t)blockIdx.x * O2 + t] = a;
    pbuf[(size_t)blockIdx.x * O2 + O + t] = bb;
  }
}

// ---------------- deterministic fp64 BN reduce + finalize ----------------
__global__ void bn_reduce_finalize(const double* __restrict__ pbuf, int nblk, int O,
                                   const float* __restrict__ g, const float* __restrict__ bb,
                                   double invcount, float* __restrict__ s_out,
                                   float* __restrict__ t_out) {
  int o = blockIdx.x * 256 + threadIdx.x;
  if (o >= O) return;
  double s1 = 0.0, s2 = 0.0;
  for (int blk = 0; blk < nblk; ++blk) {
    s1 += pbuf[(size_t)blk * 2 * O + o];
    s2 += pbuf[(size_t)blk * 2 * O + O + o];
  }
  double mean = s1 * invcount;
  double var = s2 * invcount - mean * mean;
  double s = (double)g[o] / sqrt(var + BNEPS);
  s_out[o] = (float)s;
  t_out[o] = (float)((double)bb[o] - mean * s);
}

// y = leaky(hmax*s+t) into feat column slice
__global__ void apply_kernel(const float* __restrict__ hmax, const float* __restrict__ s,
                             const float* __restrict__ tt, float* __restrict__ feat,
                             int colOff, int logO, int total) {
  int i = blockIdx.x * 256 + threadIdx.x;
  if (i >= total) return;
  int O = 1 << logO;
  int o = i & (O - 1);
  int pp = i >> logO;
  float v = hmax[i] * s[o] + tt[o];
  feat[(size_t)pp * 512 + colOff + o] = v > 0.f ? v : SLOPE * v;
}

// column partial stats over H (rows x 1024): pbuf[rb][2048] = [sum | sq] (fp64)
__global__ void colstats_kernel(const float* __restrict__ H, double* __restrict__ pbuf) {
  int o = blockIdx.x * 256 + threadIdx.x;
  int rb = blockIdx.y;
  int r0 = rb * 128;
  double s1 = 0.0, s2 = 0.0;
  for (int r = 0; r < 128; ++r) {
    double v = (double)H[(size_t)(r0 + r) * 1024 + o];
    s1 += v;
    s2 += v * v;
  }
  pbuf[(size_t)rb * 2048 + o] = s1;
  pbuf[(size_t)rb * 2048 + 1024 + o] = s2;
}

// out[b][o][n] = leaky(h5[b][n][o]*s+t)
__global__ void out_kernel(const float* __restrict__ h5, const float* __restrict__ s,
                           const float* __restrict__ tt, float* __restrict__ out) {
  __shared__ float tile[32][33];
  int b = blockIdx.z;
  int n0 = blockIdx.x * 32, o0 = blockIdx.y * 32;
  int t = threadIdx.x;
  for (int e = t; e < 1024; e += 256) {
    int rn = e >> 5, co = e & 31;
    int o = o0 + co;
    float v = h5[((size_t)b * NPTS + n0 + rn) * 1024 + o] * s[o] + tt[o];
    tile[rn][co] = v > 0.f ? v : SLOPE * v;
  }
  __syncthreads();
  for (int e = t; e < 1024; e += 256) {
    int ro = e >> 5, cn = e & 31;
    out[((size_t)b * 1024 + o0 + ro) * NPTS + n0 + cn] = tile[cn][ro];
  }
}

// ---------------- host ----------------
extern "C" void kernel_launch(void* const* d_in, const int* in_sizes, int n_in,
                              void* d_out, int out_size, void* d_ws, size_t ws_size,
                              hipStream_t stream) {
  const float* x = (const float*)d_in[0];
  const float* Wm[5] = {(const float*)d_in[1], (const float*)d_in[4], (const float*)d_in[7],
                        (const float*)d_in[10], (const float*)d_in[13]};
  const float* gv[5] = {(const float*)d_in[2], (const float*)d_in[5], (const float*)d_in[8],
                        (const float*)d_in[11], (const float*)d_in[14]};
  const float* bvv[5] = {(const float*)d_in[3], (const float*)d_in[6], (const float*)d_in[9],
                         (const float*)d_in[12], (const float*)d_in[15]};
  float* out = (float*)d_out;

  char* wsb = (char*)d_ws;
  size_t off = 0;
  auto alloc = [&](size_t bytes) -> char* {
    off = (off + 255) & ~(size_t)255;
    char* p = wsb + off;
    off += bytes;
    return p;
  };
  float* xb = (float*)alloc((size_t)BATCH * NPTS * 3 * 4);
  double* xxb = (double*)alloc((size_t)BATCH * NPTS * 8);
  int* idxb = (int*)alloc((size_t)BATCH * NPTS * KNN * 4);
  float* feat = (float*)alloc((size_t)BATCH * NPTS * 512 * 4);
  float* hmax = (float*)alloc((size_t)BATCH * NPTS * 256 * 4);
  float* h5 = (float*)alloc((size_t)BATCH * NPTS * 1024 * 4);
  float* PQ = h5;  // alias: PQ (<=8192x512) used per-layer, h5 only needed after
  float* U1 = (float*)alloc(3 * 128 * 4);
  float* U2 = (float*)alloc(64 * 128 * 4);
  float* U3 = (float*)alloc(64 * 256 * 4);
  float* U4 = (float*)alloc(128 * 512 * 4);
  float* w5t = (float*)alloc(512 * 1024 * 4);
  double* pbuf = (double*)alloc((size_t)2048 * 512 * 8);  // fp64 block partials (max O=256)
  float* stv = (float*)alloc(3072 * 4);
  off = (off + 255) & ~(size_t)255;
  size_t avail = (ws_size > off) ? (ws_size - off) : 0;
  size_t rmax = avail / ((size_t)NPTS * 4);
  int R;
  if (rmax >= NPTS) R = NPTS;
  else {
    R = (int)(rmax & ~(size_t)127);
    if (R < 128) R = 128;
  }
  float* distbuf = (float*)(wsb + off);

  float* sv[5] = {stv + 0, stv + 128, stv + 256, stv + 512, stv + 1024};
  float* tv[5] = {stv + 64, stv + 192, stv + 384, stv + 768, stv + 2048};
  float* Us[4] = {U1, U2, U3, U4};
  const int Cs[4] = {3, 64, 64, 128};
  const int Osz[4] = {64, 64, 128, 256};

  xtrans_kernel<<<(BATCH * 3 * NPTS + 255) / 256, 256, 0, stream>>>(x, xb);
  for (int l = 0; l < 4; ++l)
    uprep_kernel<<<(Cs[l] * Osz[l] + 255) / 256, 256, 0, stream>>>(Wm[l], Us[l], Osz[l], Cs[l]);
  wtrans_kernel<<<(1024 * 512 + 255) / 256, 256, 0, stream>>>(Wm[4], w5t, 1024, 512);

  auto knn = [&](const float* Xbase, int lda, int C) {
    xx_kernel<<<(BATCH * NPTS + 255) / 256, 256, 0, stream>>>(Xbase, lda, C, xxb);
    for (int b = 0; b < BATCH; ++b) {
      for (int n0 = 0; n0 < NPTS; n0 += R) {
        int rows = imin(R, NPTS - n0);
        dist64_kernel<<<dim3(NPTS / 64, rows / 64), 256, 0, stream>>>(
            Xbase + ((size_t)b * NPTS + n0) * lda, lda, Xbase + (size_t)b * NPTS * lda, lda,
            xxb + (size_t)b * NPTS + n0, xxb + (size_t)b * NPTS, distbuf, NPTS, C);
        topk_kernel<<<rows / 4, 256, 0, stream>>>(distbuf, idxb + (size_t)b * NPTS * KNN, n0, rows);
      }
    }
  };

  auto edge = [&](int li, const float* Xbase, int lda, int C, int O, int colOff) {
    knn(Xbase, lda, C);
    int O2 = 2 * O;
    gemm128<<<dim3(O2 / 128, BATCH * NPTS / 128), 256, 0, stream>>>(Xbase, lda, Us[li], O2, PQ, O2,
                                                                    C);
    int nblk = BATCH * NPTS / 4;
    if (O == 64)
      gathermax_kernel<1><<<nblk, 256, 0, stream>>>(PQ, idxb, hmax, O, pbuf);
    else if (O == 128)
      gathermax_kernel<2><<<nblk, 256, 0, stream>>>(PQ, idxb, hmax, O, pbuf);
    else
      gathermax_kernel<4><<<nblk, 256, 0, stream>>>(PQ, idxb, hmax, O, pbuf);
    bn_reduce_finalize<<<(O + 255) / 256, 256, 0, stream>>>(
        pbuf, nblk, O, gv[li], bvv[li], 1.0 / ((double)BATCH * NPTS * KNN), sv[li], tv[li]);
    int logO = (O == 64) ? 6 : (O == 128) ? 7 : 8;
    int total = BATCH * NPTS * O;
    apply_kernel<<<(total + 255) / 256, 256, 0, stream>>>(hmax, sv[li], tv[li], feat, colOff, logO,
                                                          total);
  };

  edge(0, xb, 3, 3, 64, 0);
  edge(1, feat, 512, 64, 64, 64);
  edge(2, feat + 64, 512, 64, 128, 128);
  edge(3, feat + 128, 512, 128, 256, 256);

  gemm128<<<dim3(1024 / 128, BATCH * NPTS / 128), 256, 0, stream>>>(feat, 512, w5t, 1024, h5, 1024,
                                                                    512);
  colstats_kernel<<<dim3(4, 64), 256, 0, stream>>>(h5, pbuf);
  bn_reduce_finalize<<<4, 256, 0, stream>>>(pbuf, 64, 1024, gv[4], bvv[4],
                                            1.0 / ((double)BATCH * NPTS), sv[4], tv[4]);
  out_kernel<<<dim3(NPTS / 32, 1024 / 32, BATCH), 256, 0, stream>>>(h5, sv[4], tv[4], out);
}

// Round 5
// 1485.078 us; speedup vs baseline: 2.4536x; 2.4536x over previous
//
#include <hip/hip_runtime.h>
#include <cmath>

#define KNN 20
#define NPTS 4096
#define BATCH 2
#define SLOPE 0.2f
#define BNEPS 1e-5
#define GTK 16

static __device__ __host__ inline int imin(int a, int b) { return a < b ? a : b; }

// ---------------- utility kernels ----------------
// x (B,3,N) -> xb (B,N,3)
__global__ void xtrans_kernel(const float* __restrict__ x, float* __restrict__ xb) {
  int i = blockIdx.x * 256 + threadIdx.x;
  if (i < BATCH * 3 * NPTS) {
    int b = i / (3 * NPTS);
    int r = i - b * 3 * NPTS;
    int c = r / NPTS;
    int n = r - c * NPTS;
    xb[((size_t)b * NPTS + n) * 3 + c] = x[i];
  }
}

// w (O,I) -> wt (I,O)
__global__ void wtrans_kernel(const float* __restrict__ w, float* __restrict__ wt, int O, int I) {
  int i = blockIdx.x * 256 + threadIdx.x;
  if (i < O * I) {
    int o = i / I, j = i - o * I;
    wt[(size_t)j * O + o] = w[i];
  }
}

// W (O, 2C) -> U (C, 2O): U[j][o]=W[o][j]; U[j][O+o]=W[o][C+j]-W[o][j]
__global__ void uprep_kernel(const float* __restrict__ W, float* __restrict__ U, int O, int C) {
  int i = blockIdx.x * 256 + threadIdx.x;
  if (i < C * O) {
    int j = i / O, o = i - j * O;
    float w1 = W[(size_t)o * 2 * C + j];
    float w2 = W[(size_t)o * 2 * C + C + j];
    U[(size_t)j * 2 * O + o] = w1;
    U[(size_t)j * 2 * O + O + o] = w2 - w1;
  }
}

// squared norms per point (fp64)
__global__ void xx_kernel(const float* __restrict__ X, int stride, int C, double* __restrict__ xx) {
  int i = blockIdx.x * 256 + threadIdx.x;
  if (i < BATCH * NPTS) {
    const float* r = X + (size_t)i * stride;
    double s = 0.0;
    for (int c = 0; c < C; ++c) s += (double)r[c] * (double)r[c];
    xx[i] = s;
  }
}

// ---------------- fp64-accurate distance GEMM ----------------
// dist[n][m] = (float)(2*sum_c A[n][c]*B[m][c] - xxA[n] - xxB[m]), fp64 accumulate.
// 64x64 tile, 4x4 micro, 256 threads.
__global__ __launch_bounds__(256) void dist64_kernel(const float* __restrict__ A, int lda,
                                                     const float* __restrict__ B, int ldb,
                                                     const double* __restrict__ xxA,
                                                     const double* __restrict__ xxB,
                                                     float* __restrict__ dist, int ldc, int K) {
  __shared__ double sA[GTK][66];
  __shared__ double sB[GTK][66];
  int t = threadIdx.x;
  int tx = t & 15, ty = t >> 4;
  int row0 = blockIdx.y * 64, col0 = blockIdx.x * 64;
  double acc[4][4] = {};

  for (int k0 = 0; k0 < K; k0 += GTK) {
    for (int e = t; e < 64 * GTK; e += 256) {
      int r = e >> 4, c = e & 15;
      bool ok = (k0 + c < K);
      sA[c][r] = ok ? (double)A[(size_t)(row0 + r) * lda + k0 + c] : 0.0;
      sB[c][r] = ok ? (double)B[(size_t)(col0 + r) * ldb + k0 + c] : 0.0;
    }
    __syncthreads();
#pragma unroll
    for (int kk = 0; kk < GTK; ++kk) {
      double a[4], b[4];
#pragma unroll
      for (int i = 0; i < 4; ++i) a[i] = sA[kk][ty * 4 + i];
#pragma unroll
      for (int j = 0; j < 4; ++j) b[j] = sB[kk][tx * 4 + j];
#pragma unroll
      for (int i = 0; i < 4; ++i)
#pragma unroll
        for (int j = 0; j < 4; ++j) acc[i][j] = fma(a[i], b[j], acc[i][j]);
    }
    __syncthreads();
  }

#pragma unroll
  for (int i = 0; i < 4; ++i) {
    int gr = row0 + ty * 4 + i;
    double xa = xxA[gr];
#pragma unroll
    for (int j = 0; j < 4; ++j) {
      int gc = col0 + tx * 4 + j;
      dist[(size_t)gr * ldc + gc] = (float)(2.0 * acc[i][j] - xa - xxB[gc]);
    }
  }
}

// ---------------- generic 128x128 fp32 GEMM, 8x8 micro (PQ + FC) ----------------
// C[M x N] = A[M x K] * B[K x N]; k-major swizzled LDS.
__global__ __launch_bounds__(256) void gemm128(const float* __restrict__ A, int lda,
                                               const float* __restrict__ B, int ldb,
                                               float* __restrict__ C, int ldc, int K) {
  __shared__ __align__(16) float sA[GTK][144];
  __shared__ __align__(16) float sB[GTK][144];
  int t = threadIdx.x;
  int tx = t & 15, ty = t >> 4;
  int row0 = blockIdx.y * 128, col0 = blockIdx.x * 128;
  float acc[8][8] = {};

  for (int k0 = 0; k0 < K; k0 += GTK) {
    bool fast = (k0 + GTK <= K);
    // stage A (transpose to k-major)
    if (fast) {
#pragma unroll
      for (int it = 0; it < 2; ++it) {
        int i = t + it * 256;
        int r = i >> 2, q = i & 3;
        const float4 av = *(const float4*)&A[(size_t)(row0 + r) * lda + k0 + q * 4];
        int pr = r + ((r >> 5) << 2);
        sA[q * 4 + 0][pr] = av.x;
        sA[q * 4 + 1][pr] = av.y;
        sA[q * 4 + 2][pr] = av.z;
        sA[q * 4 + 3][pr] = av.w;
      }
    } else {
#pragma unroll
      for (int it = 0; it < 2; ++it) {
        int i = t + it * 256;
        int r = i >> 2, q = i & 3;
        int pr = r + ((r >> 5) << 2);
#pragma unroll
        for (int j = 0; j < 4; ++j) {
          int k = q * 4 + j;
          sA[k][pr] = (k0 + k < K) ? A[(size_t)(row0 + r) * lda + k0 + k] : 0.f;
        }
      }
    }
    // stage B (already k-major in memory)
#pragma unroll
    for (int it = 0; it < 2; ++it) {
      int i = t + it * 256;
      int k = i >> 5, nq = (i & 31) * 4;
      int pc = nq + ((nq >> 5) << 2);
      float4 bv = make_float4(0.f, 0.f, 0.f, 0.f);
      if (k0 + k < K) bv = *(const float4*)&B[(size_t)(k0 + k) * ldb + col0 + nq];
      *(float4*)&sB[k][pc] = bv;
    }
    __syncthreads();
    int prA = ty * 8 + ((ty >> 2) << 2);
    int prB = tx * 8 + ((tx >> 2) << 2);
#pragma unroll
    for (int kk = 0; kk < GTK; ++kk) {
      float a[8], b[8];
      *(float4*)&a[0] = *(const float4*)&sA[kk][prA];
      *(float4*)&a[4] = *(const float4*)&sA[kk][prA + 4];
      *(float4*)&b[0] = *(const float4*)&sB[kk][prB];
      *(float4*)&b[4] = *(const float4*)&sB[kk][prB + 4];
#pragma unroll
      for (int i = 0; i < 8; ++i)
#pragma unroll
        for (int j = 0; j < 8; ++j) acc[i][j] += a[i] * b[j];
    }
    __syncthreads();
  }

#pragma unroll
  for (int i = 0; i < 8; ++i) {
    int gr = row0 + ty * 8 + i;
#pragma unroll
    for (int jq = 0; jq < 2; ++jq) {
      float4 o;
#pragma unroll
      for (int j = 0; j < 4; ++j) ((float*)&o)[j] = acc[i][jq * 4 + j];
      *(float4*)&C[(size_t)gr * ldc + col0 + tx * 8 + jq * 4] = o;
    }
  }
}

// ---------------- top-k: one wave per row, values in registers ----------------
__global__ __launch_bounds__(256) void topk_kernel(const float* __restrict__ dist,
                                                   int* __restrict__ idxout, int n0, int rows) {
  int wave = threadIdx.x >> 6, lane = threadIdx.x & 63;
  int row = blockIdx.x * 4 + wave;
  if (row >= rows) return;
  const float* d = dist + (size_t)row * NPTS;
  float v[16][4];
#pragma unroll
  for (int s = 0; s < 16; ++s) *(float4*)v[s] = *(const float4*)&d[s * 256 + lane * 4];
  int base = lane * 4;
  for (int it = 0; it < KNN; ++it) {
    float bv = v[0][0];
    int bi = base;
#pragma unroll
    for (int s = 0; s < 16; ++s)
#pragma unroll
      for (int c = 0; c < 4; ++c) {
        if (s == 0 && c == 0) continue;
        float x = v[s][c];
        if (x > bv) { bv = x; bi = s * 256 + base + c; }
      }
#pragma unroll
    for (int off = 1; off < 64; off <<= 1) {
      float ov = __shfl_xor(bv, off);
      int oi = __shfl_xor(bi, off);
      if (ov > bv || (ov == bv && oi < bi)) { bv = ov; bi = oi; }
    }
    if (lane == 0) idxout[(size_t)(n0 + row) * KNN + it] = bi;
#pragma unroll
    for (int s = 0; s < 16; ++s)
#pragma unroll
      for (int c = 0; c < 4; ++c)
        if (s * 256 + base + c == bi) v[s][c] = -__builtin_inff();
  }
}

// ---------------- gather-max + per-block fp64 BN partial stats ----------------
// h[n,k,o] = P[idx[n,k],o] + Q[n,o]; PQ row = [P | Q] (stride 2O). One wave per point.
// Block partials (fp64) to pbuf[blk][2*O] = [sum | sumsq].
template <int NO>
__global__ __launch_bounds__(256) void gathermax_kernel(const float* __restrict__ PQ,
                                                        const int* __restrict__ idx,
                                                        float* __restrict__ hmax, int O,
                                                        double* __restrict__ pbuf) {
  __shared__ double sh1[4][256];
  __shared__ double sh2[4][256];
  int t = threadIdx.x;
  int wave = t >> 6, lane = t & 63;
  int pt = blockIdx.x * 4 + wave;
  int b = pt >> 12;
  int O2 = 2 * O;
  int iv = idx[(size_t)pt * KNN + (lane % KNN)];
  const float* Qp = PQ + (size_t)pt * O2 + O + lane * NO;
  float q[NO], mx[NO];
  double s1[NO], s2[NO];
#pragma unroll
  for (int c = 0; c < NO; ++c) {
    q[c] = Qp[c];
    mx[c] = -__builtin_inff();
    s1[c] = 0.0;
    s2[c] = 0.0;
  }
#pragma unroll
  for (int k = 0; k < KNN; ++k) {
    int m = __shfl(iv, k);
    const float* Pp = PQ + ((size_t)(b << 12) + m) * O2 + lane * NO;
    float p[NO];
#pragma unroll
    for (int c = 0; c < NO; ++c) p[c] = Pp[c];
#pragma unroll
    for (int c = 0; c < NO; ++c) {
      float h = p[c] + q[c];
      mx[c] = fmaxf(mx[c], h);
      double hd = (double)h;
      s1[c] += hd;
      s2[c] += hd * hd;
    }
  }
  float* Hp = hmax + (size_t)pt * O + lane * NO;
#pragma unroll
  for (int c = 0; c < NO; ++c) {
    Hp[c] = mx[c];
    sh1[wave][lane * NO + c] = s1[c];
    sh2[wave][lane * NO + c] = s2[c];
  }
  __syncthreads();
  if (t < O) {
    double a = 0.0, bb = 0.0;
#pragma unroll
    for (int w = 0; w < 4; ++w) {
      a += sh1[w][t];
      bb += sh2[w][t];
    }
    pbuf[(size_t)blockIdx.x * O2 + t] = a;
    pbuf[(size_t)blockIdx.x * O2 + O + t] = bb;
  }
}

// ---------------- deterministic parallel fp64 BN reduce + finalize ----------------
// grid.x = O blocks, 256 threads. Thread t sums rows t, t+256, ... then fixed-order
// LDS tree reduce. Deterministic (fixed assignment + fixed association).
__global__ __launch_bounds__(256) void bn_reduce_finalize(const double* __restrict__ pbuf,
                                                          int nblk, int O,
                                                          const float* __restrict__ g,
                                                          const float* __restrict__ bb,
                                                          double invcount,
                                                          float* __restrict__ s_out,
                                                          float* __restrict__ t_out) {
  __shared__ double sh1[256];
  __shared__ double sh2[256];
  int o = blockIdx.x;
  int t = threadIdx.x;
  double s1 = 0.0, s2 = 0.0;
  for (int blk = t; blk < nblk; blk += 256) {
    s1 += pbuf[(size_t)blk * 2 * O + o];
    s2 += pbuf[(size_t)blk * 2 * O + O + o];
  }
  sh1[t] = s1;
  sh2[t] = s2;
  __syncthreads();
  for (int s = 128; s > 0; s >>= 1) {
    if (t < s) {
      sh1[t] += sh1[t + s];
      sh2[t] += sh2[t + s];
    }
    __syncthreads();
  }
  if (t == 0) {
    double mean = sh1[0] * invcount;
    double var = sh2[0] * invcount - mean * mean;
    double s = (double)g[o] / sqrt(var + BNEPS);
    s_out[o] = (float)s;
    t_out[o] = (float)((double)bb[o] - mean * s);
  }
}

// y = leaky(hmax*s+t) into feat column slice
__global__ void apply_kernel(const float* __restrict__ hmax, const float* __restrict__ s,
                             const float* __restrict__ tt, float* __restrict__ feat,
                             int colOff, int logO, int total) {
  int i = blockIdx.x * 256 + threadIdx.x;
  if (i >= total) return;
  int O = 1 << logO;
  int o = i & (O - 1);
  int pp = i >> logO;
  float v = hmax[i] * s[o] + tt[o];
  feat[(size_t)pp * 512 + colOff + o] = v > 0.f ? v : SLOPE * v;
}

// column partial stats over H (rows x 1024): pbuf[rb][2048] = [sum | sq] (fp64)
__global__ void colstats_kernel(const float* __restrict__ H, double* __restrict__ pbuf) {
  int o = blockIdx.x * 256 + threadIdx.x;
  int rb = blockIdx.y;
  int r0 = rb * 128;
  double s1 = 0.0, s2 = 0.0;
  for (int r = 0; r < 128; ++r) {
    double v = (double)H[(size_t)(r0 + r) * 1024 + o];
    s1 += v;
    s2 += v * v;
  }
  pbuf[(size_t)rb * 2048 + o] = s1;
  pbuf[(size_t)rb * 2048 + 1024 + o] = s2;
}

// out[b][o][n] = leaky(h5[b][n][o]*s+t)
__global__ void out_kernel(const float* __restrict__ h5, const float* __restrict__ s,
                           const float* __restrict__ tt, float* __restrict__ out) {
  __shared__ float tile[32][33];
  int b = blockIdx.z;
  int n0 = blockIdx.x * 32, o0 = blockIdx.y * 32;
  int t = threadIdx.x;
  for (int e = t; e < 1024; e += 256) {
    int rn = e >> 5, co = e & 31;
    int o = o0 + co;
    float v = h5[((size_t)b * NPTS + n0 + rn) * 1024 + o] * s[o] + tt[o];
    tile[rn][co] = v > 0.f ? v : SLOPE * v;
  }
  __syncthreads();
  for (int e = t; e < 1024; e += 256) {
    int ro = e >> 5, cn = e & 31;
    out[((size_t)b * 1024 + o0 + ro) * NPTS + n0 + cn] = tile[cn][ro];
  }
}

// ---------------- host ----------------
extern "C" void kernel_launch(void* const* d_in, const int* in_sizes, int n_in,
                              void* d_out, int out_size, void* d_ws, size_t ws_size,
                              hipStream_t stream) {
  const float* x = (const float*)d_in[0];
  const float* Wm[5] = {(const float*)d_in[1], (const float*)d_in[4], (const float*)d_in[7],
                        (const float*)d_in[10], (const float*)d_in[13]};
  const float* gv[5] = {(const float*)d_in[2], (const float*)d_in[5], (const float*)d_in[8],
                        (const float*)d_in[11], (const float*)d_in[14]};
  const float* bvv[5] = {(const float*)d_in[3], (const float*)d_in[6], (const float*)d_in[9],
                         (const float*)d_in[12], (const float*)d_in[15]};
  float* out = (float*)d_out;

  char* wsb = (char*)d_ws;
  size_t off = 0;
  auto alloc = [&](size_t bytes) -> char* {
    off = (off + 255) & ~(size_t)255;
    char* p = wsb + off;
    off += bytes;
    return p;
  };
  float* xb = (float*)alloc((size_t)BATCH * NPTS * 3 * 4);
  double* xxb = (double*)alloc((size_t)BATCH * NPTS * 8);
  int* idxb = (int*)alloc((size_t)BATCH * NPTS * KNN * 4);
  float* feat = (float*)alloc((size_t)BATCH * NPTS * 512 * 4);
  float* hmax = (float*)alloc((size_t)BATCH * NPTS * 256 * 4);
  float* h5 = (float*)alloc((size_t)BATCH * NPTS * 1024 * 4);
  float* PQ = h5;  // alias: PQ (<=8192x512) used per-layer, h5 only needed after
  float* U1 = (float*)alloc(3 * 128 * 4);
  float* U2 = (float*)alloc(64 * 128 * 4);
  float* U3 = (float*)alloc(64 * 256 * 4);
  float* U4 = (float*)alloc(128 * 512 * 4);
  float* w5t = (float*)alloc(512 * 1024 * 4);
  double* pbuf = (double*)alloc((size_t)2048 * 512 * 8);  // fp64 block partials (max O=256)
  float* stv = (float*)alloc(3072 * 4);
  off = (off + 255) & ~(size_t)255;
  size_t avail = (ws_size > off) ? (ws_size - off) : 0;
  size_t rmax = avail / ((size_t)NPTS * 4);
  int R;
  if (rmax >= NPTS) R = NPTS;
  else {
    R = (int)(rmax & ~(size_t)127);
    if (R < 128) R = 128;
  }
  float* distbuf = (float*)(wsb + off);

  float* sv[5] = {stv + 0, stv + 128, stv + 256, stv + 512, stv + 1024};
  float* tv[5] = {stv + 64, stv + 192, stv + 384, stv + 768, stv + 2048};
  float* Us[4] = {U1, U2, U3, U4};
  const int Cs[4] = {3, 64, 64, 128};
  const int Osz[4] = {64, 64, 128, 256};

  xtrans_kernel<<<(BATCH * 3 * NPTS + 255) / 256, 256, 0, stream>>>(x, xb);
  for (int l = 0; l < 4; ++l)
    uprep_kernel<<<(Cs[l] * Osz[l] + 255) / 256, 256, 0, stream>>>(Wm[l], Us[l], Osz[l], Cs[l]);
  wtrans_kernel<<<(1024 * 512 + 255) / 256, 256, 0, stream>>>(Wm[4], w5t, 1024, 512);

  auto knn = [&](const float* Xbase, int lda, int C) {
    xx_kernel<<<(BATCH * NPTS + 255) / 256, 256, 0, stream>>>(Xbase, lda, C, xxb);
    for (int b = 0; b < BATCH; ++b) {
      for (int n0 = 0; n0 < NPTS; n0 += R) {
        int rows = imin(R, NPTS - n0);
        dist64_kernel<<<dim3(NPTS / 64, rows / 64), 256, 0, stream>>>(
            Xbase + ((size_t)b * NPTS + n0) * lda, lda, Xbase + (size_t)b * NPTS * lda, lda,
            xxb + (size_t)b * NPTS + n0, xxb + (size_t)b * NPTS, distbuf, NPTS, C);
        topk_kernel<<<rows / 4, 256, 0, stream>>>(distbuf, idxb + (size_t)b * NPTS * KNN, n0, rows);
      }
    }
  };

  auto edge = [&](int li, const float* Xbase, int lda, int C, int O, int colOff) {
    knn(Xbase, lda, C);
    int O2 = 2 * O;
    gemm128<<<dim3(O2 / 128, BATCH * NPTS / 128), 256, 0, stream>>>(Xbase, lda, Us[li], O2, PQ, O2,
                                                                    C);
    int nblk = BATCH * NPTS / 4;
    if (O == 64)
      gathermax_kernel<1><<<nblk, 256, 0, stream>>>(PQ, idxb, hmax, O, pbuf);
    else if (O == 128)
      gathermax_kernel<2><<<nblk, 256, 0, stream>>>(PQ, idxb, hmax, O, pbuf);
    else
      gathermax_kernel<4><<<nblk, 256, 0, stream>>>(PQ, idxb, hmax, O, pbuf);
    bn_reduce_finalize<<<O, 256, 0, stream>>>(pbuf, nblk, O, gv[li], bvv[li],
                                              1.0 / ((double)BATCH * NPTS * KNN), sv[li], tv[li]);
    int logO = (O == 64) ? 6 : (O == 128) ? 7 : 8;
    int total = BATCH * NPTS * O;
    apply_kernel<<<(total + 255) / 256, 256, 0, stream>>>(hmax, sv[li], tv[li], feat, colOff, logO,
                                                          total);
  };

  edge(0, xb, 3, 3, 64, 0);
  edge(1, feat, 512, 64, 64, 64);
  edge(2, feat + 64, 512, 64, 128, 128);
  edge(3, feat + 128, 512, 128, 256, 256);

  gemm128<<<dim3(1024 / 128, BATCH * NPTS / 128), 256, 0, stream>>>(feat, 512, w5t, 1024, h5, 1024,
                                                                    512);
  colstats_kernel<<<dim3(4, 64), 256, 0, stream>>>(h5, pbuf);
  bn_reduce_finalize<<<1024, 256, 0, stream>>>(pbuf, 64, 1024, gv[4], bvv[4],
                                               1.0 / ((double)BATCH * NPTS), sv[4], tv[4]);
  out_kernel<<<dim3(NPTS / 32, 1024 / 32, BATCH), 256, 0, stream>>>(h5, sv[4], tv[4], out);
}